// Round 13
// baseline (354.571 us; speedup 1.0000x reference)
//
#include <hip/hip_runtime.h>
#include <stdint.h>

// out[8192,4096] = x @ (Wd + Ws)^T, fp32 device buffers (harness upcasts fp16).
// Wd,Ws elementwise complementary -> W = Wd+Ws exact, fp16-representable.
// Path A (ws >= 96MB): fused cvt -> bf16 in ws, then 128x256 MFMA GEMM,
//   BK=32, triple-buffered LDS (72KB -> 2 blocks/CU), 4 waves/SIMD target,
//   counted vmcnt(3), st_16x32 swizzle (0-conflict), swapped-operand stores.
//   Mechanism: two independent blocks per CU put waves at DIFFERENT phases ->
//   one block's LDS burst overlaps the other's MFMA burst (r4-r12 showed the
//   single-block barrier-locked config serializes the two pipes at ~51%).
// Path B: round-3-verified fused reg-staged GEMM (fallback, f16).

#define NT 8192
#define NO 4096
#define NK 4096

typedef float f32x4 __attribute__((ext_vector_type(4)));
typedef _Float16 f16x8 __attribute__((ext_vector_type(8)));
typedef __bf16 bf16x8 __attribute__((ext_vector_type(8)));
typedef short short8 __attribute__((ext_vector_type(8)));

__device__ __forceinline__ void gload_lds16(const void* g, void* l) {
  __builtin_amdgcn_global_load_lds(
      (const __attribute__((address_space(1))) void*)g,
      (__attribute__((address_space(3))) void*)l, 16, 0, 0);
}

#define BAR() __builtin_amdgcn_s_barrier()
#define WV3() asm volatile("s_waitcnt vmcnt(3)" ::: "memory")
#define WV0() asm volatile("s_waitcnt vmcnt(0)" ::: "memory")
#define PRIO1() __builtin_amdgcn_s_setprio(1)
#define PRIO0() __builtin_amdgcn_s_setprio(0)

__device__ __forceinline__ short f32_bf16(float f) {
  uint32_t u = __float_as_uint(f);
  u += 0x7FFFu + ((u >> 16) & 1u);  // RNE
  return (short)(u >> 16);
}

// ---- pre-pass: fp32 -> bf16, x and W=Wd+Ws in one launch ----
__global__ __launch_bounds__(256) void cvt_all(
    const float* __restrict__ x, const float* __restrict__ wd,
    const float* __restrict__ ws, short* __restrict__ xh,
    short* __restrict__ wh, int nx8, int nw8) {
  int i = blockIdx.x * 256 + threadIdx.x;
  if (i < nx8) {
    const f32x4* p = (const f32x4*)x + 2 * (size_t)i;
    f32x4 lo = p[0], hi = p[1];
    short8 r;
#pragma unroll
    for (int j = 0; j < 4; ++j) { r[j] = f32_bf16(lo[j]); r[j + 4] = f32_bf16(hi[j]); }
    *((short8*)xh + i) = r;
  } else {
    int j8 = i - nx8;
    if (j8 < nw8) {
      const f32x4* pd = (const f32x4*)wd + 2 * (size_t)j8;
      const f32x4* ps = (const f32x4*)ws + 2 * (size_t)j8;
      f32x4 dl = pd[0], dh = pd[1], sl = ps[0], sh = ps[1];
      short8 r;
#pragma unroll
      for (int j = 0; j < 4; ++j) {
        r[j] = f32_bf16(dl[j] + sl[j]);      // add exact: one addend is +/-0
        r[j + 4] = f32_bf16(dh[j] + sh[j]);
      }
      *((short8*)wh + j8) = r;
    }
  }
}

// ---- 128x256 GEMM, BK=32, triple-buffer, 1 phase per K-tile ----
// 8 waves (2Mx4N), per-wave out 64x64 (acc = 16 x f32x4 = 64 regs).
// LDS buf = A(128x32, 8KB) + B(256x32, 2x8KB) = 24KB; 3 bufs = 72KB.
// Each 8KB region: 8 subtiles of 16 rows x 32 halves (1KB), st_16x32 XOR
// (verified 0-conflict geometry, identical to r5-r12). Staging: linear
// global_load_lds dest + inverse-swizzled global source.

#define RD_OCC(BUF_) do { \
  const char* Ab_ = ldsc + (BUF_) * 24576 + aoff; \
  const char* Bb_ = ldsc + (BUF_) * 24576 + boff; \
  br[0] = *(const short8*)(Bb_ + 0);    ar[0] = *(const short8*)(Ab_ + 0); \
  br[1] = *(const short8*)(Bb_ + 1024); br[2] = *(const short8*)(Bb_ + 2048); \
  br[3] = *(const short8*)(Bb_ + 3072); ar[1] = *(const short8*)(Ab_ + 1024); \
  ar[2] = *(const short8*)(Ab_ + 2048); ar[3] = *(const short8*)(Ab_ + 3072); \
} while (0)

#define STG_OCC(BUF_, KCOL) do { \
  gload_lds16(Xrow + (KCOL), ldsc + (BUF_) * 24576 + t16); \
  gload_lds16(Wrow + (KCOL), ldsc + (BUF_) * 24576 + 8192 + t16); \
  gload_lds16(Wrow + 128 * NK + (KCOL), ldsc + (BUF_) * 24576 + 16384 + t16); \
} while (0)

// swapped operands: D-row = W rows (N), D-col = X rows (M) -> contiguous-N acc
#define MM_OCC() do { PRIO1(); _Pragma("unroll") \
  for (int m = 0; m < 4; ++m) _Pragma("unroll") for (int n = 0; n < 4; ++n) \
    acc[m][n] = __builtin_amdgcn_mfma_f32_16x16x32_bf16( \
        __builtin_bit_cast(bf16x8, br[n]), __builtin_bit_cast(bf16x8, ar[m]), \
        acc[m][n], 0, 0, 0); \
  PRIO0(); } while (0)

__global__ __launch_bounds__(512, 4) void gemm_occ(
    const short* __restrict__ Xg, const short* __restrict__ Wg,
    float* __restrict__ C) {
  __shared__ short lds[3][12288];  // 3 x 24KB = 72KB -> 2 blocks/CU
  char* ldsc = (char*)&lds[0][0];

  const int t = threadIdx.x;      // 0..511
  const int lane = t & 63;
  const int wv = t >> 6;          // 0..7
  const int wr = wv >> 2;         // 0..1  (M half, 64 rows)
  const int wc = wv & 3;          // 0..3  (N quarter, 64 cols)
  const int fr = lane & 15;
  const int kq = lane >> 4;       // 0..3
  const int t16 = t * 16;

  // XCD-aware bijective swizzle (nwg = 1024 = 8*128)
  const int swz = (blockIdx.x & 7) * 128 + (blockIdx.x >> 3);
  const int bm = swz >> 4, bn = swz & 15;   // 64 x 16 tiles
  const int brow = bm * 128, bcol = bn * 256;

  // staging: invert st_16x32 swizzle within the 8KB region (128r x 32k)
  const int o = t16;
  const int sub = o >> 10;                           // 16-row group 0..7
  const int inner = o & 1023;
  const int innsw = inner ^ (((inner >> 9) & 1) << 5);
  const int rloc = sub * 16 + ((innsw >> 6) & 15);   // 0..127
  const int kloc = (innsw >> 1) & 31;                // 0..31, 8-granular

  const short* Xrow = Xg + (brow + rloc) * NK + kloc;
  const short* Wrow = Wg + (bcol + rloc) * NK + kloc;  // B rows 0..127 (+128*NK for H1)

  // fragment read offsets (same verified 0-conflict pattern)
  const int finner = ((fr << 6) | (kq << 4)) ^ ((fr & 8) << 2);
  const int aoff = wr * 4096 + finner;                          // A: rsub = wr*4+m
  const int boff = 8192 + (wc >> 1) * 8192 + (wc & 1) * 4096 + finner;  // B: rsub=(wc&1)*4+n

  short8 ar[4], br[4];
  f32x4 acc[4][4] = {};

  // ---- prologue: tile0 -> buf0, tile1 -> buf1 (6 loads in flight) ----
  STG_OCC(0, 0);
  STG_OCC(1, 32);
  WV3(); BAR();   // tile0's 3 loads complete

#pragma unroll 1
  for (int i = 0; i < 42; ++i) {     // phases t = 3i..3i+2, tiles 0..125
    const int kc = i * 96;
    // phase 3i: read buf0 (tile 3i), stage tile 3i+2 -> buf2
    RD_OCC(0); STG_OCC(2, kc + 64);
    MM_OCC(); WV3(); BAR();
    // phase 3i+1: read buf1, stage 3i+3 -> buf0
    RD_OCC(1); STG_OCC(0, kc + 96);
    MM_OCC(); WV3(); BAR();
    // phase 3i+2: read buf2, stage 3i+4 -> buf1
    RD_OCC(2); STG_OCC(1, kc + 128);
    MM_OCC(); WV3(); BAR();
  }
  // peeled: tile 126 (buf0), tile 127 (buf1)
  RD_OCC(0); MM_OCC(); WV0(); BAR();
  RD_OCC(1); MM_OCC();

  // Swapped-operand C/D: row = brow + wr*64 + m*16 + fr (M);
  // col = bcol + wc*64 + n*16 + kq*4 + [0,4) (N, contiguous f32x4)
  const long r0 = brow + wr * 64 + fr;
  const int c0 = bcol + wc * 64 + kq * 4;
#pragma unroll
  for (int m = 0; m < 4; ++m)
#pragma unroll
    for (int n = 0; n < 4; ++n)
      *(f32x4*)(C + (r0 + m * 16) * NO + c0 + n * 16) = acc[m][n];
}

// ---- fallback (round-3 verified): fused reg-staged 128^2 GEMM (f16) ----
__global__ __launch_bounds__(256) void gemm_fb(
    const float* __restrict__ Xf, const float* __restrict__ Wdf,
    const float* __restrict__ Wsf, float* __restrict__ C) {
  __shared__ _Float16 lsA[128 * 32];
  __shared__ _Float16 lsB[128 * 32];

  const int t = threadIdx.x;
  const int lane = t & 63;
  const int wid = t >> 6;
  const int wr = wid >> 1, wc = wid & 1;

  const int nwg = (NT / 128) * (NO / 128);  // 2048
  const int swz = (blockIdx.x & 7) * (nwg >> 3) + (blockIdx.x >> 3);
  const int nbn = NO / 128;
  const int bm = swz / nbn, bn = swz % nbn;
  const long brow = (long)bm * 128, bcol = (long)bn * 128;

  const int srow = t >> 2;
  const int scol = (t & 3) * 8;
  const float* X  = Xf + (brow + srow) * (long)NK + scol;
  const float* Wd = Wdf + (bcol + srow) * (long)NK + scol;
  const float* Ws = Wsf + (bcol + srow) * (long)NK + scol;
  _Float16* lA = lsA + t * 8;
  _Float16* lB = lsB + t * 8;

  const int fr = lane & 15;
  const int kg = (lane >> 4) * 8;
  const _Float16* pA = lsA + (wr * 64 + fr) * 32 + kg;
  const _Float16* pB = lsB + (wc * 64 + fr) * 32 + kg;

  f32x4 acc[4][4] = {};

  for (int k0 = 0; k0 < NK; k0 += 32) {
    f32x4 aL0 = *(const f32x4*)(X + k0),  aH0 = *(const f32x4*)(X + k0 + 4);
    f32x4 aL1 = *(const f32x4*)(X + k0 + 64 * NK), aH1 = *(const f32x4*)(X + k0 + 64 * NK + 4);
    f32x4 dL0 = *(const f32x4*)(Wd + k0), dH0 = *(const f32x4*)(Wd + k0 + 4);
    f32x4 sL0 = *(const f32x4*)(Ws + k0), sH0 = *(const f32x4*)(Ws + k0 + 4);
    f32x4 dL1 = *(const f32x4*)(Wd + k0 + 64 * NK), dH1 = *(const f32x4*)(Wd + k0 + 64 * NK + 4);
    f32x4 sL1 = *(const f32x4*)(Ws + k0 + 64 * NK), sH1 = *(const f32x4*)(Ws + k0 + 64 * NK + 4);
    __syncthreads();
    f16x8 va0, va1, vb0, vb1;
#pragma unroll
    for (int j = 0; j < 4; ++j) {
      va0[j] = (_Float16)aL0[j];            va0[j + 4] = (_Float16)aH0[j];
      va1[j] = (_Float16)aL1[j];            va1[j + 4] = (_Float16)aH1[j];
      vb0[j] = (_Float16)(dL0[j] + sL0[j]); vb0[j + 4] = (_Float16)(dH0[j] + sH0[j]);
      vb1[j] = (_Float16)(dL1[j] + sL1[j]); vb1[j + 4] = (_Float16)(dH1[j] + sH1[j]);
    }
    *(f16x8*)lA = va0;
    *(f16x8*)(lA + 64 * 32) = va1;
    *(f16x8*)lB = vb0;
    *(f16x8*)(lB + 64 * 32) = vb1;
    __syncthreads();
    f16x8 af[4], bf[4];
#pragma unroll
    for (int i2 = 0; i2 < 4; ++i2) af[i2] = *(const f16x8*)(pA + i2 * 16 * 32);
#pragma unroll
    for (int i2 = 0; i2 < 4; ++i2) bf[i2] = *(const f16x8*)(pB + i2 * 16 * 32);
#pragma unroll
    for (int i2 = 0; i2 < 4; ++i2)
#pragma unroll
      for (int j2 = 0; j2 < 4; ++j2)
        acc[i2][j2] = __builtin_amdgcn_mfma_f32_16x16x32_f16(af[i2], bf[j2], acc[i2][j2], 0, 0, 0);
  }

  const int fq = lane >> 4;
#pragma unroll
  for (int i2 = 0; i2 < 4; ++i2)
#pragma unroll
    for (int j2 = 0; j2 < 4; ++j2)
#pragma unroll
      for (int r = 0; r < 4; ++r) {
        long row = brow + wr * 64 + i2 * 16 + fq * 4 + r;
        long col = bcol + wc * 64 + j2 * 16 + fr;
        C[row * NO + col] = acc[i2][j2][r];
      }
}

extern "C" void kernel_launch(void* const* d_in, const int* in_sizes, int n_in,
                              void* d_out, int out_size, void* d_ws, size_t ws_size,
                              hipStream_t stream) {
  const float* x   = (const float*)d_in[0];
  const float* wd  = (const float*)d_in[1];
  const float* wsp = (const float*)d_in[2];
  float* out = (float*)d_out;

  const size_t xh_bytes = (size_t)NT * NK * 2;  // 64 MiB
  const size_t wh_bytes = (size_t)NO * NK * 2;  // 32 MiB

  if (d_ws != nullptr && ws_size >= xh_bytes + wh_bytes) {
    short* xh = (short*)d_ws;
    short* wh = (short*)((char*)d_ws + xh_bytes);
    const int nx8 = NT * NK / 8;  // 4,194,304
    const int nw8 = NO * NK / 8;  // 2,097,152
    cvt_all<<<(nx8 + nw8) / 256, 256, 0, stream>>>(x, wd, wsp, xh, wh, nx8, nw8);
    gemm_occ<<<(NT / 128) * (NO / 256), 512, 0, stream>>>(xh, wh, out);
  } else {
    gemm_fb<<<(NT / 128) * (NO / 128), 256, 0, stream>>>(x, wd, wsp, out);
  }
}